// Round 1
// baseline (147.402 us; speedup 1.0000x reference)
//
#include <hip/hip_runtime.h>

// Problem constants (match reference)
constexpr int T     = 4;
constexpr int NROWS = 1000000;
constexpr int B     = 16384;
constexpr int TOTAL = 16384 * 50; // 819200 lookups per table

typedef float fv4 __attribute__((ext_vector_type(4)));
typedef int   iv4 __attribute__((ext_vector_type(4)));

// ws layout: p[T*NROWS] floats (16 MB)

// Producer: p[t*NROWS + r] = dot(table[t][r], W).
// XCD-pinned with the SAME mapping as pool (table t -> XCDs {2t, 2t+1}) so
// the p slice is written dirty into exactly the L2 pool will gather from.
// Table reads are non-temporal (streaming, 8 MB/XCD) so they don't evict
// the 4 MB p slice being produced into the same L2.
// 4 rows/thread: 4x fv4 NT loads, one fv4 (16B) store.
// Fused out[:] = bias init (pool's atomics accumulate on top of bias).
__global__ __launch_bounds__(256)
void produce_kernel(const fv4*   __restrict__ tables,
                    const float* __restrict__ Wp,
                    const float* __restrict__ bias,
                    float* __restrict__ p,
                    float* __restrict__ out) {
    // 3912 blocks = 8 * 489. xcd = blockIdx&7; table = xcd>>1.
    const int xcd    = blockIdx.x & 7;
    const int t      = xcd >> 1;
    const int within = ((blockIdx.x >> 3) << 1) + (xcd & 1);   // [0, 978)
    const int r0     = within * 1024 + threadIdx.x * 4;        // 4 consecutive rows

    if (r0 < NROWS) {                                          // r0 % 4 == 0 -> r0+3 <= 999999
        const float wx = Wp[0], wy = Wp[1], wz = Wp[2], ww = Wp[3];
        const fv4* src = tables + t * NROWS + r0;
        const fv4 a = __builtin_nontemporal_load(&src[0]);
        const fv4 b = __builtin_nontemporal_load(&src[1]);
        const fv4 c = __builtin_nontemporal_load(&src[2]);
        const fv4 d = __builtin_nontemporal_load(&src[3]);
        fv4 res;
        res.x = a.x * wx + a.y * wy + a.z * wz + a.w * ww;
        res.y = b.x * wx + b.y * wy + b.z * wz + b.w * ww;
        res.z = c.x * wx + c.y * wy + c.z * wz + c.w * ww;
        res.w = d.x * wx + d.y * wy + d.z * wz + d.w * ww;
        *(fv4*)&p[t * NROWS + r0] = res;                       // normal store: stay in L2
    }
    const int flat = blockIdx.x * 256 + threadIdx.x;
    if (flat < T * B) out[flat] = bias[0];
}

// Pool: 4 lookups per thread via int4 NT loads. In-lane conditional prefix
// over the 4 sorted segment ids, then a 64-lane segmented inclusive scan on
// each lane's tail run (valid because segs are sorted => equal keys are
// contiguous). Internal run boundaries (rare: ~2% of lanes) flush directly;
// the last lane of each tail run flushes the scanned sum.
// XCD-pinned identically to produce: gathers hit the local L2's warm p slice.
__global__ __launch_bounds__(256)
void pool_kernel(const float* __restrict__ p,        // [T*NROWS]
                 const iv4*   __restrict__ indices,  // [T*TOTAL/4]
                 const iv4*   __restrict__ segids,   // [T*TOTAL/4] sorted per table
                 float*       __restrict__ out)      // [T*B], pre-set to bias
{
    // 3200 blocks: 800 per table (1024 lookups each), blockIdx&7 ~ XCD id.
    const int xcd    = blockIdx.x & 7;
    const int t      = xcd >> 1;
    const int within = ((blockIdx.x >> 3) << 1) + (xcd & 1);   // [0, 800)
    const int q      = within * 256 + threadIdx.x;             // quad index [0, 204800)
    const int gq     = t * (TOTAL / 4) + q;
    const int lane   = threadIdx.x & 63;

    const iv4 s4 = __builtin_nontemporal_load(&segids[gq]);
    const iv4 i4 = __builtin_nontemporal_load(&indices[gq]);

    const float* pt = p + t * NROWS;
    const float v0 = pt[i4.x];
    const float v1 = pt[i4.y];
    const float v2 = pt[i4.z];
    const float v3 = pt[i4.w];

    // In-lane conditional prefix (runs reset at seg boundaries).
    const float a0 = v0;
    const float a1 = v1 + (s4.y == s4.x ? a0 : 0.f);
    const float a2 = v2 + (s4.z == s4.y ? a1 : 0.f);
    const float a3 = v3 + (s4.w == s4.z ? a2 : 0.f);

    // Cross-lane segmented inclusive scan on (key = tail seg, val = tail-run sum).
    // Sorted keys => if key[lane-d] == key[lane], everything between matches too,
    // and any lane with an internal boundary has a key that first appears inside
    // it (so the scan never pulls across a boundary).
    float x   = a3;
    int   key = s4.w;
    #pragma unroll
    for (int d = 1; d < 64; d <<= 1) {
        const float ov = __shfl_up(x, d, 64);
        const int   ok = __shfl_up(key, d, 64);
        if (lane >= d && ok == key) x += ov;
    }

    // Carry entering this lane's FIRST run (from previous lane's tail run).
    const float xprev = __shfl_up(x, 1, 64);
    const int   kprev = __shfl_up(key, 1, 64);
    const float carry = (lane > 0 && kprev == s4.x) ? xprev : 0.f;

    float* outt = out + t * B;
    // Internal run flushes: run ends at item k iff s[k] != s[k+1]. Carry applies
    // only if the run started at item 0 (s[k] == s[0]).
    if (s4.x != s4.y) atomicAdd(&outt[s4.x], a0 + carry);
    if (s4.y != s4.z) atomicAdd(&outt[s4.y], a1 + (s4.y == s4.x ? carry : 0.f));
    if (s4.z != s4.w) atomicAdd(&outt[s4.z], a2 + (s4.z == s4.x ? carry : 0.f));

    // Tail flush: last lane of each tail-run (next lane's first seg differs).
    // x already contains the carry via the scan when the lane is uniform, and
    // tail runs that start mid-lane correctly get no cross-lane contribution.
    const int snext = __shfl_down(s4.x, 1, 64);
    if (lane == 63 || snext != key) atomicAdd(&outt[key], x);
}

extern "C" void kernel_launch(void* const* d_in, const int* in_sizes, int n_in,
                              void* d_out, int out_size, void* d_ws, size_t ws_size,
                              hipStream_t stream) {
    const fv4*   tables  = (const fv4*)d_in[0];      // [T, N, 4] f32
    const float* W       = (const float*)d_in[1];    // [1, 4]   f32
    const float* bias    = (const float*)d_in[2];    // [1]      f32
    const iv4*   indices = (const iv4*)d_in[3];      // [T, TOTAL]
    const iv4*   segids  = (const iv4*)d_in[4];      // [T, TOTAL] sorted per table
    float*       out     = (float*)d_out;            // [T*B] f32

    float* p = (float*)d_ws;                         // 16 MB scratch

    // 3912 = 8*489 blocks; 4 rows/thread; covers 4M rows + 65536 out-init.
    produce_kernel<<<3912, 256, 0, stream>>>(tables, W, bias, p, out);
    // 3200 = 8*400 blocks; 4 lookups/thread = 3,276,800 lookups.
    pool_kernel<<<3200, 256, 0, stream>>>(p, indices, segids, out);
}

// Round 2
// 143.903 us; speedup vs baseline: 1.0243x; 1.0243x over previous
//
#include <hip/hip_runtime.h>

// Problem constants (match reference)
constexpr int T     = 4;
constexpr int NROWS = 1000000;
constexpr int B     = 16384;
constexpr int TOTAL = 16384 * 50; // 819200 lookups per table

typedef float fv4 __attribute__((ext_vector_type(4)));

// Tiny init: out[:] = bias (atomics in pool accumulate on top).
// 64 blocks x 256 threads, one fv4 per thread = 65536 floats.
__global__ __launch_bounds__(256)
void init_kernel(const float* __restrict__ bias, fv4* __restrict__ out) {
    const int i = blockIdx.x * 256 + threadIdx.x;   // [0, 16384)
    const float b = bias[0];
    fv4 v; v.x = b; v.y = b; v.z = b; v.w = b;
    out[i] = v;
}

// Pool, direct-gather form: one lookup per thread. Gather the 16B table row,
// dot with W inline (dot and segment-sum commute), wave-level segmented
// inclusive scan over sorted segment ids, last lane of each run flushes via
// atomicAdd. No intermediate p array: the produce kernel's 80 MB round-trip
// (64 MB table read + 16 MB p write + 16 MB p re-read) is deleted.
// XCD-pinned: table t -> XCD pair {2t,2t+1}, so each XCD's L2 caches only its
// own 16 MB table slice (vs 64 MB unpinned); rows are L3-warm from the input
// restore. idx/seg streams are non-temporal so 26 MB doesn't evict gather lines.
__global__ __launch_bounds__(256)
void pool_kernel(const fv4*   __restrict__ tables,   // [T*NROWS] rows of 16B
                 const float* __restrict__ Wp,       // [4]
                 const int*   __restrict__ indices,  // [T*TOTAL]
                 const int*   __restrict__ segids,   // [T*TOTAL] sorted per table
                 float*       __restrict__ out)      // [T*B], pre-set to bias
{
    // 12800 blocks: 3200 per table (256 lookups each). blockIdx%8 ~ XCD id.
    const int xcd    = blockIdx.x & 7;
    const int t      = xcd >> 1;
    const int within = ((blockIdx.x >> 3) << 1) + (xcd & 1);   // [0, 3200)
    const int local  = within * 256 + threadIdx.x;             // [0, TOTAL)
    const int g      = t * TOTAL + local;

    const int lane = threadIdx.x & 63;

    const int seg = __builtin_nontemporal_load(&segids[g]);
    const int idx = __builtin_nontemporal_load(&indices[g]);

    // Gather row (cached: L2 slice-local + L3-warm) and project.
    const fv4 r = tables[t * NROWS + idx];
    const float wx = Wp[0], wy = Wp[1], wz = Wp[2], ww = Wp[3];
    float v = r.x * wx + r.y * wy + r.z * wz + r.w * ww;

    // Segmented inclusive scan across the 64-lane wave (sorted segs => equal
    // keys contiguous, so the conditional Hillis-Steele never crosses a run).
    #pragma unroll
    for (int d = 1; d < 64; d <<= 1) {
        const float ov = __shfl_up(v, d, 64);
        const int   os = __shfl_up(seg, d, 64);
        if (lane >= d && os == seg) v += ov;
    }

    // Last lane of each same-seg run in this wave flushes the run sum.
    // ~102k atomics over 65k addresses => ~2 per address, no serialization.
    const int nseg = __shfl_down(seg, 1, 64);
    if (lane == 63 || nseg != seg) {
        atomicAdd(&out[t * B + seg], v);
    }
}

extern "C" void kernel_launch(void* const* d_in, const int* in_sizes, int n_in,
                              void* d_out, int out_size, void* d_ws, size_t ws_size,
                              hipStream_t stream) {
    const fv4*   tables  = (const fv4*)d_in[0];      // [T, N, 4] f32
    const float* W       = (const float*)d_in[1];    // [1, 4]   f32
    const float* bias    = (const float*)d_in[2];    // [1]      f32
    const int*   indices = (const int*)d_in[3];      // [T, TOTAL]
    const int*   segids  = (const int*)d_in[4];      // [T, TOTAL] sorted per table
    float*       out     = (float*)d_out;            // [T*B] f32

    (void)d_ws; (void)ws_size;                       // no workspace needed anymore

    // 65536 floats = 16384 fv4 -> 64 blocks. Must precede pool (same stream).
    init_kernel<<<64, 256, 0, stream>>>(bias, (fv4*)out);

    // T*TOTAL = 3,276,800 threads = 12,800 blocks (multiple of 8 for pinning)
    pool_kernel<<<12800, 256, 0, stream>>>(tables, W, indices, segids, out);
}

// Round 3
// 133.574 us; speedup vs baseline: 1.1035x; 1.0773x over previous
//
#include <hip/hip_runtime.h>

// Problem constants (match reference)
constexpr int T     = 4;
constexpr int NROWS = 1000000;
constexpr int B     = 16384;
constexpr int TOTAL = 16384 * 50; // 819200 lookups per table

typedef float fv4 __attribute__((ext_vector_type(4)));
typedef int   iv2 __attribute__((ext_vector_type(2)));

// ws layout: p[T*NROWS] floats (16 MB)

// Producer (round-0 proven form, unchanged): p[t*NROWS+r] = dot(table[t][r], W).
// Dense 16B/lane cached loads (tables are L3-warm from the input restore);
// measurement (r1 vs r0) showed nontemporal table loads REGRESS — keep cached.
// Compressing 64 MB tables -> 16 MB p is what makes pool's gathers L2-resident
// (4 MB slice/table == one XCD's L2); round-2 measured the alternative
// (direct 16B gathers over 64 MB): 52 us, 163 MB fetch, latency-bound. Worse.
// Fused out[:] = bias init (pool's atomics accumulate on top of bias).
__global__ __launch_bounds__(256)
void produce_kernel(const fv4*   __restrict__ tables,
                    const float* __restrict__ Wp,
                    const float* __restrict__ bias,
                    float* __restrict__ p,
                    float* __restrict__ out) {
    const int i = blockIdx.x * 256 + threadIdx.x;
    if (i < T * NROWS) {
        const float wx = Wp[0], wy = Wp[1], wz = Wp[2], ww = Wp[3];
        const fv4 r = tables[i];
        p[i] = r.x * wx + r.y * wy + r.z * wz + r.w * ww;  // normal store: stay cached
    }
    if (i < T * B) out[i] = bias[0];
}

// Pool: 2 lookups/thread via int2 NT loads. Two INDEPENDENT gathers per thread
// (2x memory-level parallelism on the latency-bound idx->gather chain), in-lane
// pair combine, then the 64-lane segmented inclusive scan on each lane's tail
// run (sorted segs => equal keys contiguous, scan never crosses a boundary).
// Internal run boundary (s0 != s1) flushes directly with the cross-lane carry;
// last lane of each tail run flushes the scanned sum.
// XCD-pinned: table t -> XCD pair {2t,2t+1} so each XCD's 4 MiB L2 holds its
// table's 4 MB p slice; idx/seg streams are non-temporal so 26 MB doesn't
// evict the p lines (each p line is re-touched ~13x).
__global__ __launch_bounds__(256)
void pool_kernel(const float* __restrict__ p,        // [T*NROWS]
                 const iv2*   __restrict__ indices,  // [T*TOTAL/2]
                 const iv2*   __restrict__ segids,   // [T*TOTAL/2] sorted per table
                 float*       __restrict__ out)      // [T*B], pre-set to bias
{
    // 6400 blocks = 8 * 800: 1600 per table (512 lookups each). blockIdx&7 ~ XCD.
    const int xcd    = blockIdx.x & 7;
    const int t      = xcd >> 1;
    const int within = ((blockIdx.x >> 3) << 1) + (xcd & 1);   // [0, 1600)
    const int q      = within * 256 + threadIdx.x;             // pair idx [0, 409600)
    const int gq     = t * (TOTAL / 2) + q;
    const int lane   = threadIdx.x & 63;

    const iv2 s2 = __builtin_nontemporal_load(&segids[gq]);
    const iv2 i2 = __builtin_nontemporal_load(&indices[gq]);

    const float* pt = p + t * NROWS;
    const float v0 = pt[i2.x];          // two independent gathers: 2x MLP
    const float v1 = pt[i2.y];

    const int s0 = s2.x, s1 = s2.y;

    // In-lane pair combine (run resets at the internal boundary).
    const float a0 = v0;
    const float a1 = v1 + (s1 == s0 ? v0 : 0.f);

    // Cross-lane segmented inclusive scan on (key = tail seg, val = tail-run sum).
    // Sorted keys: if key[lane-d]==key[lane] everything between matches too, and
    // a tail run that starts mid-lane has a key no earlier lane holds.
    float x   = a1;
    int   key = s1;
    #pragma unroll
    for (int d = 1; d < 64; d <<= 1) {
        const float ov = __shfl_up(x, d, 64);
        const int   ok = __shfl_up(key, d, 64);
        if (lane >= d && ok == key) x += ov;
    }

    // Carry entering this lane's FIRST element (prev lane's scanned tail sum).
    const float xprev = __shfl_up(x, 1, 64);
    const int   kprev = __shfl_up(key, 1, 64);
    const float carry = (lane > 0 && kprev == s0) ? xprev : 0.f;

    float* outt = out + t * B;
    // Internal boundary: run ending at element 0 flushes (with cross-lane carry).
    if (s0 != s1) atomicAdd(&outt[s0], a0 + carry);

    // Tail flush: last lane of each tail run (next lane's first seg differs).
    // When the lane is uniform the scan already folded the carry into x; when
    // the tail run started mid-lane it correctly got no cross-lane contribution.
    const int snext = __shfl_down(s0, 1, 64);
    if (lane == 63 || snext != key) atomicAdd(&outt[key], x);
}

extern "C" void kernel_launch(void* const* d_in, const int* in_sizes, int n_in,
                              void* d_out, int out_size, void* d_ws, size_t ws_size,
                              hipStream_t stream) {
    const fv4*   tables  = (const fv4*)d_in[0];      // [T, N, 4] f32
    const float* W       = (const float*)d_in[1];    // [1, 4]   f32
    const float* bias    = (const float*)d_in[2];    // [1]      f32
    const iv2*   indices = (const iv2*)d_in[3];      // [T, TOTAL]
    const iv2*   segids  = (const iv2*)d_in[4];      // [T, TOTAL] sorted per table
    float*       out     = (float*)d_out;            // [T*B] f32

    float* p = (float*)d_ws;                         // 16 MB scratch

    {
        int n = T * NROWS;                           // 4,000,000 (covers T*B init too)
        produce_kernel<<<(n + 255) / 256, 256, 0, stream>>>(tables, W, bias, p, out);
    }
    {
        // T*TOTAL/2 = 1,638,400 threads = 6,400 blocks (multiple of 8 for pinning)
        pool_kernel<<<6400, 256, 0, stream>>>(p, indices, segids, out);
    }
}